// Round 1
// baseline (215.397 us; speedup 1.0000x reference)
//
#include <hip/hip_runtime.h>
#include <type_traits>

// ---------------------------------------------------------------------------
// BlockChunkedActivityRoutedNet: pipeline
//   K1 activity:   act[c] = sum |x[:, c*512:(c+1)*512]|          (8 sums)
//   K2 topk:       idx[0..1] = top-2 chunks (desc, ties->lower)
//   K3 gather_x:   xb (4096x1024 bf16) = x[:, idx[k]*512 ...]    (topk order)
//   K4 transpose:  wct (2x512x512 bf16)  = W_chunks[idx[k]]^T
//   K5 transpose:  wft (4096x1024 bf16)  = W_final^T
//   K6 GEMM1:      h (4096x1024 bf16)  = xb @ Wc + b_chunks[idx] (z=2 batched)
//   K7 GEMM2:      out (4096x4096 f32) = h @ W_final + b_final
// All GEMMs: 128x128 tile, BK=64, v_mfma_f32_16x16x32_bf16, B^T input.
// ---------------------------------------------------------------------------

typedef __bf16 bf16x8_t __attribute__((ext_vector_type(8)));
typedef float  f32x4_t  __attribute__((ext_vector_type(4)));

__device__ inline unsigned short f2bf(float f) {
    __bf16 b = (__bf16)f;
    return __builtin_bit_cast(unsigned short, b);
}

// ---------------- K1: per-chunk sum of |x| --------------------------------
__global__ void activity_kernel(const float* __restrict__ x, float* __restrict__ act) {
    // grid (64, 8), block 256. chunk = blockIdx.y; each block does 64 rows.
    const int chunk = blockIdx.y;
    const int tid = threadIdx.x;
    const int colf4 = tid & 127;   // 128 float4 per 512-col chunk
    const int rsub = tid >> 7;     // 0..1
    const float4* base = (const float4*)x + (size_t)chunk * 128 + colf4;
    float s = 0.f;
    #pragma unroll 4
    for (int i = 0; i < 32; ++i) {
        int row = blockIdx.x * 64 + i * 2 + rsub;
        float4 v = base[(size_t)row * 1024];
        s += fabsf(v.x) + fabsf(v.y) + fabsf(v.z) + fabsf(v.w);
    }
    #pragma unroll
    for (int off = 32; off > 0; off >>= 1) s += __shfl_down(s, off, 64);
    __shared__ float wsum[4];
    if ((tid & 63) == 0) wsum[tid >> 6] = s;
    __syncthreads();
    if (tid == 0) atomicAdd(&act[chunk], wsum[0] + wsum[1] + wsum[2] + wsum[3]);
}

// ---------------- K2: top-2 of 8 ------------------------------------------
__global__ void topk_kernel(const float* __restrict__ act, int* __restrict__ idx) {
    if (threadIdx.x == 0) {
        float v0 = -1e30f, v1 = -1e30f; int b0 = 0, b1 = 0;
        for (int i = 0; i < 8; ++i) {
            float v = act[i];
            if (v > v0) { v1 = v0; b1 = b0; v0 = v; b0 = i; }
            else if (v > v1) { v1 = v; b1 = i; }
        }
        idx[0] = b0; idx[1] = b1;
    }
}

// ---------------- K3: gather selected chunks of x -> bf16 ------------------
__global__ void gather_x_kernel(const float* __restrict__ x, const int* __restrict__ idx,
                                unsigned short* __restrict__ xb) {
    int t = blockIdx.x * blockDim.x + threadIdx.x;   // 4096*256 threads
    int row = t >> 8;
    int c4 = (t & 255) * 4;                          // 0..1020
    int kk = c4 >> 9;
    int scol = idx[kk] * 512 + (c4 & 511);
    float4 v = *(const float4*)(x + (size_t)row * 4096 + scol);
    ushort4 o;
    o.x = f2bf(v.x); o.y = f2bf(v.y); o.z = f2bf(v.z); o.w = f2bf(v.w);
    *(ushort4*)(xb + (size_t)row * 1024 + c4) = o;
}

// ---------------- K4/K5: transpose + convert fp32 -> bf16 ------------------
// dst[c][r] = (bf16) src[r][c];  src is RxC row-major; R,C multiples of 32.
// If idx != nullptr: src += idx[blockIdx.z]*chunk_elems; dst += blockIdx.z*chunk_elems.
__global__ void transpose_cvt_kernel(const float* __restrict__ src, unsigned short* __restrict__ dst,
                                     int R, int C, const int* __restrict__ idx, int chunk_elems) {
    if (idx) { src += (size_t)idx[blockIdx.z] * chunk_elems; dst += (size_t)blockIdx.z * chunk_elems; }
    __shared__ float tile[32][33];
    const int tx = threadIdx.x, ty = threadIdx.y;
    const int cb = blockIdx.x * 32, rb = blockIdx.y * 32;
    #pragma unroll
    for (int i = 0; i < 4; ++i)
        tile[ty + i * 8][tx] = src[(size_t)(rb + ty + i * 8) * C + cb + tx];
    __syncthreads();
    #pragma unroll
    for (int i = 0; i < 4; ++i)
        dst[(size_t)(cb + ty + i * 8) * R + rb + tx] = f2bf(tile[tx][ty + i * 8]);
}

// ---------------- K6/K7: bf16 MFMA GEMM, B^T layout ------------------------
// C[m][n] = sum_k A[m][k] * Bt[n][k] + bias[n]
#define BM 128
#define BN 128
#define BKT 64
#define LDT 72   // padded LDS stride (144 B): b128 reads hit all 8 bank groups

template <typename OutT>
__global__ __launch_bounds__(256, 2)
void gemm_bt_kernel(const unsigned short* __restrict__ A, int lda, int aOffZ,
                    const unsigned short* __restrict__ Bt, int ldb, int bOffZ,
                    OutT* __restrict__ C, int ldc, int cOffZ,
                    const float* __restrict__ biasBase, int biasStride,
                    const int* __restrict__ idxPtr, int K) {
    const int z = blockIdx.z;
    A  += (size_t)z * aOffZ;
    Bt += (size_t)z * bOffZ;
    C  += (size_t)z * cOffZ;
    const float* bias = biasBase + (idxPtr ? (size_t)idxPtr[z] * biasStride : 0);

    __shared__ unsigned short As[BM * LDT];
    __shared__ unsigned short Bs[BN * LDT];

    const int tid = threadIdx.x;
    const int wave = tid >> 6;
    const int lane = tid & 63;
    const int m0 = blockIdx.x * BM;
    const int n0 = blockIdx.y * BN;
    const int wm = (wave >> 1) * 64;   // wave row within tile
    const int wn = (wave & 1) * 64;    // wave col within tile

    f32x4_t acc[4][4] = {};

    const int sr = tid >> 3;           // staging row 0..31 per pass
    const int sc = (tid & 7) * 8;      // staging col 0..56

    for (int k0 = 0; k0 < K; k0 += BKT) {
        #pragma unroll
        for (int p = 0; p < 4; ++p) {
            int r = p * 32 + sr;
            uint4 va = *(const uint4*)(A  + (size_t)(m0 + r) * lda + k0 + sc);
            uint4 vb = *(const uint4*)(Bt + (size_t)(n0 + r) * ldb + k0 + sc);
            *(uint4*)(As + r * LDT + sc) = va;
            *(uint4*)(Bs + r * LDT + sc) = vb;
        }
        __syncthreads();
        #pragma unroll
        for (int kq = 0; kq < 2; ++kq) {
            const int kb = kq * 32 + ((lane >> 4) * 8);
            bf16x8_t af[4], bfr[4];
            #pragma unroll
            for (int i = 0; i < 4; ++i) {
                af[i]  = *(const bf16x8_t*)(As + (wm + i * 16 + (lane & 15)) * LDT + kb);
                bfr[i] = *(const bf16x8_t*)(Bs + (wn + i * 16 + (lane & 15)) * LDT + kb);
            }
            #pragma unroll
            for (int mi = 0; mi < 4; ++mi)
                #pragma unroll
                for (int ni = 0; ni < 4; ++ni)
                    acc[mi][ni] = __builtin_amdgcn_mfma_f32_16x16x32_bf16(af[mi], bfr[ni], acc[mi][ni], 0, 0, 0);
        }
        __syncthreads();
    }

    // epilogue: D row = (lane>>4)*4 + reg, col = lane&15  (within each 16x16)
    const int row_l = (lane >> 4) * 4;
    const int col_l = lane & 15;
    #pragma unroll
    for (int mi = 0; mi < 4; ++mi) {
        #pragma unroll
        for (int ni = 0; ni < 4; ++ni) {
            int col = n0 + wn + ni * 16 + col_l;
            float bv = bias[col];
            #pragma unroll
            for (int j = 0; j < 4; ++j) {
                int row = m0 + wm + mi * 16 + row_l + j;
                float v = acc[mi][ni][j] + bv;
                if constexpr (std::is_same<OutT, unsigned short>::value)
                    C[(size_t)row * ldc + col] = f2bf(v);
                else
                    C[(size_t)row * ldc + col] = v;
            }
        }
    }
}

// ---------------------------------------------------------------------------
extern "C" void kernel_launch(void* const* d_in, const int* in_sizes, int n_in,
                              void* d_out, int out_size, void* d_ws, size_t ws_size,
                              hipStream_t stream) {
    const float* x    = (const float*)d_in[0];   // (4096, 4096)
    const float* Wc   = (const float*)d_in[1];   // (8, 512, 512)
    const float* bc   = (const float*)d_in[2];   // (8, 512)
    const float* Wf   = (const float*)d_in[3];   // (1024, 4096)
    const float* bfin = (const float*)d_in[4];   // (4096,)
    float* out = (float*)d_out;                  // (4096, 4096) fp32

    // workspace layout (needs ~25.1 MB)
    float* act = (float*)d_ws;
    int*   idx = (int*)((char*)d_ws + 64);
    unsigned short* xb  = (unsigned short*)((char*)d_ws + 256);  // 4096x1024 bf16
    unsigned short* h   = xb  + (size_t)4096 * 1024;             // 4096x1024 bf16
    unsigned short* wct = h   + (size_t)4096 * 1024;             // 2x512x512 bf16 (transposed)
    unsigned short* wft = wct + (size_t)2 * 512 * 512;           // 4096x1024 bf16 (Wf^T)

    hipMemsetAsync(d_ws, 0, 64, stream);  // zero activities

    activity_kernel<<<dim3(64, 8), 256, 0, stream>>>(x, act);
    topk_kernel<<<1, 64, 0, stream>>>(act, idx);
    gather_x_kernel<<<4096, 256, 0, stream>>>(x, idx, xb);
    transpose_cvt_kernel<<<dim3(16, 16, 2), dim3(32, 8), 0, stream>>>(Wc, wct, 512, 512, idx, 512 * 512);
    transpose_cvt_kernel<<<dim3(128, 32, 1), dim3(32, 8), 0, stream>>>(Wf, wft, 1024, 4096, nullptr, 0);

    // GEMM1: h[:, z*512:(z+1)*512] = xb[:, z*512:] @ Wc[idx[z]] + bc[idx[z]]
    gemm_bt_kernel<unsigned short><<<dim3(32, 4, 2), 256, 0, stream>>>(
        xb, 1024, 512, wct, 512, 512 * 512, h, 1024, 512, bc, 512, idx, 512);

    // GEMM2: out = h @ Wf + b_final
    gemm_bt_kernel<float><<<dim3(32, 32, 1), 256, 0, stream>>>(
        h, 1024, 0, wft, 1024, 0, out, 4096, 0, bfin, 0, nullptr, 1024);
}

// Round 2
// 193.116 us; speedup vs baseline: 1.1154x; 1.1154x over previous
//
#include <hip/hip_runtime.h>

// ---------------------------------------------------------------------------
// BlockChunkedActivityRoutedNet pipeline (R2):
//   K1 activity:  part[c*64+b] = partial sum |x[rows_b, chunk c]|
//   K2 topk:      reduce partials -> act[8] -> idx[0..1] (top-2 desc)
//   K3 transWc:   wct (2x512x512 bf16) = W_chunks[idx[z]]^T
//   K4 transWf:   wft (4096x1024 bf16) = W_final^T
//   K5 GEMM1:     h (4096x1024 bf16) = x[:, idx[z]] @ Wc + bc   (fused gather,
//                 64x64 tile, A: fp32->bf16 VGPR staging, B: global_load_lds)
//   K6 GEMM2:     out (4096x4096 f32) = h @ Wf + b_final
//                 (128x128 tile, BK=64, both operands via global_load_lds w=16,
//                  XOR-swizzled LDS -> conflict-free ds_read_b128)
// ---------------------------------------------------------------------------

typedef __bf16 bf16x8_t __attribute__((ext_vector_type(8)));
typedef float  f32x4_t  __attribute__((ext_vector_type(4)));

__device__ inline unsigned short f2bf(float f) {
    __bf16 b = (__bf16)f;
    return __builtin_bit_cast(unsigned short, b);
}

// ---- LDS tile helpers: BK=64 bf16 per row (128 B), 8 granules of 16 B ----
// slot(row, gs) holds global granule gg = gs ^ (row & 7)  (XOR swizzle)

// async stage of 8 rows (wave-uniform row0) from bf16 global, 16 B/lane
__device__ inline void stage_glds(const unsigned short* gtile, int stride, int row0,
                                  unsigned short* lds, int lane) {
    const int r8 = lane >> 3;              // row within segment
    const int gg = (lane & 7) ^ r8;        // swizzled global granule
    const unsigned short* gp = gtile + (size_t)(row0 + r8) * stride + gg * 8;
    unsigned short* lp = lds + row0 * 64;  // wave-uniform base; HW adds lane*16B
    __builtin_amdgcn_global_load_lds((const __attribute__((address_space(1))) void*)gp,
                                     (__attribute__((address_space(3))) void*)lp,
                                     16, 0, 0);
}

// swizzled fragment read: 8 bf16 at (row, k=kb..kb+7), kb multiple of 8
__device__ inline bf16x8_t ldsfrag(const unsigned short* Ls, int row, int kb) {
    return *(const bf16x8_t*)(Ls + row * 64 + (((kb >> 3) ^ (row & 7)) * 8));
}

// ---------------- K1: per-chunk partial sums of |x| ------------------------
__global__ void activity_kernel(const float* __restrict__ x, float* __restrict__ part) {
    const int chunk = blockIdx.y;
    const int tid = threadIdx.x;
    const int colf4 = tid & 127;   // 128 float4 per 512-col chunk
    const int rsub = tid >> 7;     // 0..1
    const float4* base = (const float4*)x + (size_t)chunk * 128 + colf4;
    float s = 0.f;
    #pragma unroll 4
    for (int i = 0; i < 32; ++i) {
        int row = blockIdx.x * 64 + i * 2 + rsub;
        float4 v = base[(size_t)row * 1024];
        s += fabsf(v.x) + fabsf(v.y) + fabsf(v.z) + fabsf(v.w);
    }
    #pragma unroll
    for (int off = 32; off > 0; off >>= 1) s += __shfl_down(s, off, 64);
    __shared__ float wsum[4];
    if ((tid & 63) == 0) wsum[tid >> 6] = s;
    __syncthreads();
    if (tid == 0) part[chunk * 64 + blockIdx.x] = wsum[0] + wsum[1] + wsum[2] + wsum[3];
}

// ---------------- K2: reduce partials, top-2 of 8 --------------------------
__global__ void topk_kernel(const float* __restrict__ part, int* __restrict__ idx) {
    __shared__ float act[8];
    const int lane = threadIdx.x & 63;
    const int wave = threadIdx.x >> 6;     // = chunk, 8 waves
    float s = part[wave * 64 + lane];
    #pragma unroll
    for (int off = 32; off > 0; off >>= 1) s += __shfl_down(s, off, 64);
    if (lane == 0) act[wave] = s;
    __syncthreads();
    if (threadIdx.x == 0) {
        float v0 = -1e30f, v1 = -1e30f; int b0 = 0, b1 = 0;
        for (int i = 0; i < 8; ++i) {
            float v = act[i];
            if (v > v0) { v1 = v0; b1 = b0; v0 = v; b0 = i; }
            else if (v > v1) { v1 = v; b1 = i; }
        }
        idx[0] = b0; idx[1] = b1;
    }
}

// ---------------- K3/K4: transpose + convert fp32 -> bf16 ------------------
__global__ void transpose_cvt_kernel(const float* __restrict__ src, unsigned short* __restrict__ dst,
                                     int R, int C, const int* __restrict__ idx, int chunk_elems) {
    if (idx) { src += (size_t)idx[blockIdx.z] * chunk_elems; dst += (size_t)blockIdx.z * chunk_elems; }
    __shared__ float tile[32][33];
    const int tx = threadIdx.x, ty = threadIdx.y;
    const int cb = blockIdx.x * 32, rb = blockIdx.y * 32;
    #pragma unroll
    for (int i = 0; i < 4; ++i)
        tile[ty + i * 8][tx] = src[(size_t)(rb + ty + i * 8) * C + cb + tx];
    __syncthreads();
    #pragma unroll
    for (int i = 0; i < 4; ++i)
        dst[(size_t)(cb + ty + i * 8) * R + rb + tx] = f2bf(tile[tx][ty + i * 8]);
}

// ---------------- K5: GEMM1, 64x64 tile, fused gather ----------------------
// h[m][z*512+n] = sum_k x[m][idx[z]*512+k] * wct[z][n][k] + bc[idx[z]][n]
__global__ __launch_bounds__(256, 2)
void gemm1_kernel(const float* __restrict__ x, const unsigned short* __restrict__ wct,
                  const float* __restrict__ bc, const int* __restrict__ idx,
                  unsigned short* __restrict__ h) {
    const int z = blockIdx.z;
    const int idxz = idx[z];
    const int m0 = blockIdx.x * 64;
    const int n0 = blockIdx.y * 64;

    __shared__ unsigned short As[64 * 64];
    __shared__ unsigned short Bs[64 * 64];

    const int tid = threadIdx.x;
    const int wave = tid >> 6;
    const int lane = tid & 63;
    const int wm = (wave >> 1) * 32;
    const int wn = (wave & 1) * 32;
    const int rl = lane & 15;
    const int quad = lane >> 4;

    const float* xtile = x + (size_t)m0 * 4096 + idxz * 512;
    const unsigned short* bttile = wct + (size_t)z * 512 * 512 + (size_t)n0 * 512;

    f32x4_t acc[2][2] = {};

    const int ar = tid >> 2;          // A staging row 0..63
    const int aq = tid & 3;           // granule pair

    for (int k0 = 0; k0 < 512; k0 += 64) {
        // B: async global->LDS, 8 segments of 8 rows
        #pragma unroll
        for (int s = wave; s < 8; s += 4)
            stage_glds(bttile + k0, 512, s * 8, Bs, lane);
        // A: fp32 -> bf16 via VGPRs, 2 granules (16 elems) per thread
        const float* gr = xtile + (size_t)ar * 4096 + k0;
        #pragma unroll
        for (int j = 0; j < 2; ++j) {
            int gg = aq * 2 + j;
            float4 a = *(const float4*)(gr + gg * 8);
            float4 b = *(const float4*)(gr + gg * 8 + 4);
            bf16x8_t v;
            v[0] = (__bf16)a.x; v[1] = (__bf16)a.y; v[2] = (__bf16)a.z; v[3] = (__bf16)a.w;
            v[4] = (__bf16)b.x; v[5] = (__bf16)b.y; v[6] = (__bf16)b.z; v[7] = (__bf16)b.w;
            *(bf16x8_t*)(As + ar * 64 + ((gg ^ (ar & 7)) * 8)) = v;
        }
        __syncthreads();
        #pragma unroll
        for (int kq = 0; kq < 2; ++kq) {
            const int kb = kq * 32 + quad * 8;
            bf16x8_t af[2], bfr[2];
            #pragma unroll
            for (int i = 0; i < 2; ++i) {
                af[i]  = ldsfrag(As, wm + i * 16 + rl, kb);
                bfr[i] = ldsfrag(Bs, wn + i * 16 + rl, kb);
            }
            #pragma unroll
            for (int mi = 0; mi < 2; ++mi)
                #pragma unroll
                for (int ni = 0; ni < 2; ++ni)
                    acc[mi][ni] = __builtin_amdgcn_mfma_f32_16x16x32_bf16(af[mi], bfr[ni], acc[mi][ni], 0, 0, 0);
        }
        __syncthreads();
    }

    const int row_l = quad * 4;
    const float* bias = bc + (size_t)idxz * 512;
    #pragma unroll
    for (int ni = 0; ni < 2; ++ni) {
        int col = n0 + wn + ni * 16 + rl;
        float bv = bias[col];
        #pragma unroll
        for (int mi = 0; mi < 2; ++mi) {
            #pragma unroll
            for (int j = 0; j < 4; ++j) {
                int row = m0 + wm + mi * 16 + row_l + j;
                h[(size_t)row * 1024 + z * 512 + col] = f2bf(acc[mi][ni][j] + bv);
            }
        }
    }
}

// ---------------- K6: GEMM2, 128x128 tile, all-async staging ---------------
// out[m][n] = sum_k h[m][k] * wft[n][k] + b_final[n]
__global__ __launch_bounds__(256, 2)
void gemm2_kernel(const unsigned short* __restrict__ A, const unsigned short* __restrict__ Bt,
                  const float* __restrict__ bias, float* __restrict__ C) {
    const int m0 = blockIdx.x * 128;
    const int n0 = blockIdx.y * 128;

    __shared__ unsigned short As[128 * 64];
    __shared__ unsigned short Bs[128 * 64];

    const int tid = threadIdx.x;
    const int wave = tid >> 6;
    const int lane = tid & 63;
    const int wm = (wave >> 1) * 64;
    const int wn = (wave & 1) * 64;
    const int rl = lane & 15;
    const int quad = lane >> 4;

    const unsigned short* Atile = A + (size_t)m0 * 1024;
    const unsigned short* Btile = Bt + (size_t)n0 * 1024;

    f32x4_t acc[4][4] = {};

    for (int k0 = 0; k0 < 1024; k0 += 64) {
        // 32 segments of 8 rows (16 A + 16 B), 8 async stages per wave
        #pragma unroll
        for (int s = wave; s < 32; s += 4) {
            if (s < 16) stage_glds(Atile + k0, 1024, s * 8, As, lane);
            else        stage_glds(Btile + k0, 1024, (s - 16) * 8, Bs, lane);
        }
        __syncthreads();
        #pragma unroll
        for (int kq = 0; kq < 2; ++kq) {
            const int kb = kq * 32 + quad * 8;
            bf16x8_t af[4], bfr[4];
            #pragma unroll
            for (int i = 0; i < 4; ++i) {
                af[i]  = ldsfrag(As, wm + i * 16 + rl, kb);
                bfr[i] = ldsfrag(Bs, wn + i * 16 + rl, kb);
            }
            #pragma unroll
            for (int mi = 0; mi < 4; ++mi)
                #pragma unroll
                for (int ni = 0; ni < 4; ++ni)
                    acc[mi][ni] = __builtin_amdgcn_mfma_f32_16x16x32_bf16(af[mi], bfr[ni], acc[mi][ni], 0, 0, 0);
        }
        __syncthreads();
    }

    const int row_l = quad * 4;
    float bv[4];
    #pragma unroll
    for (int ni = 0; ni < 4; ++ni) bv[ni] = bias[n0 + wn + ni * 16 + rl];
    #pragma unroll
    for (int mi = 0; mi < 4; ++mi) {
        #pragma unroll
        for (int ni = 0; ni < 4; ++ni) {
            int col = n0 + wn + ni * 16 + rl;
            #pragma unroll
            for (int j = 0; j < 4; ++j) {
                int row = m0 + wm + mi * 16 + row_l + j;
                C[(size_t)row * 4096 + col] = acc[mi][ni][j] + bv[ni];
            }
        }
    }
}

// ---------------------------------------------------------------------------
extern "C" void kernel_launch(void* const* d_in, const int* in_sizes, int n_in,
                              void* d_out, int out_size, void* d_ws, size_t ws_size,
                              hipStream_t stream) {
    const float* x    = (const float*)d_in[0];   // (4096, 4096)
    const float* Wc   = (const float*)d_in[1];   // (8, 512, 512)
    const float* bc   = (const float*)d_in[2];   // (8, 512)
    const float* Wf   = (const float*)d_in[3];   // (1024, 4096)
    const float* bfin = (const float*)d_in[4];   // (4096,)
    float* out = (float*)d_out;                  // (4096, 4096) fp32

    // workspace layout (~17 MB)
    float* part = (float*)d_ws;                                   // 512 f32
    int*   idx  = (int*)((char*)d_ws + 2048);                     // 2 int
    unsigned short* h   = (unsigned short*)((char*)d_ws + 4096);  // 4096x1024 bf16
    unsigned short* wct = h   + (size_t)4096 * 1024;              // 2x512x512 bf16 (Wc^T, z-major)
    unsigned short* wft = wct + (size_t)2 * 512 * 512;            // 4096x1024 bf16 (Wf^T)

    activity_kernel<<<dim3(64, 8), 256, 0, stream>>>(x, part);
    topk_kernel<<<1, 512, 0, stream>>>(part, idx);
    transpose_cvt_kernel<<<dim3(16, 16, 2), dim3(32, 8), 0, stream>>>(Wc, wct, 512, 512, idx, 512 * 512);
    transpose_cvt_kernel<<<dim3(128, 32, 1), dim3(32, 8), 0, stream>>>(Wf, wft, 1024, 4096, nullptr, 0);

    gemm1_kernel<<<dim3(64, 8, 2), 256, 0, stream>>>(x, wct, bc, idx, h);
    gemm2_kernel<<<dim3(32, 32, 1), 256, 0, stream>>>(h, wft, bfin, out);
}